// Round 12
// baseline (2082.522 us; speedup 1.0000x reference)
//
#include <hip/hip_runtime.h>
#include <math.h>

#define T_SEQ 120
#define BATCH 256
#define HID   512
#define G3    1536            // 3*HID
#define MROWS (BATCH*T_SEQ)   // 30720
#define TS    (T_SEQ*HID)     // 61440, row stride per batch in out buffers
#define KGATE 122880          // T_SEQ*2*HID
#define CSTRIDE 32            // counter stride (ints) -> one per 128B

typedef __attribute__((ext_vector_type(8))) short bf16x8;
typedef __attribute__((ext_vector_type(4))) float f32x4;

__device__ __forceinline__ unsigned short f2bf(float f) {
    union { float f; unsigned u; } x; x.f = f;
    unsigned r = x.u + 0x7fffu + ((x.u >> 16) & 1u);   // RNE
    return (unsigned short)(r >> 16);
}
__device__ __forceinline__ float bf2f(unsigned short u) {
    union { unsigned u; float f; } x; x.u = ((unsigned)u) << 16; return x.f;
}
__device__ __forceinline__ float sigm_fast(float x) {
    return 1.f / (1.f + __expf(-x));
}
__device__ __forceinline__ float tanh_fast(float x) {
    float e = __expf(2.f * x);
    return 1.f - 2.f / (e + 1.f);
}

// ---------------------------------------------------------------------------
__global__ void build_x(const float* __restrict__ X_lag,
                        const float* __restrict__ X_cov,
                        float* __restrict__ x_in)
{
    int idx = blockIdx.x * 256 + threadIdx.x;      // < 30720*64
    int d = idx & 63;
    int m = idx >> 6;                               // b*120 + t
    int b = m / 120, t = m - b * 120;
    float v;
    if (d < 32) v = X_lag[((size_t)t * BATCH + b) * 32 + d];
    else        v = X_cov[((size_t)t * BATCH + b) * 32 + (d - 32)];
    x_in[idx] = v;
}

__global__ void cast_whh0(const float* __restrict__ W, unsigned short* __restrict__ o)
{
    int i = blockIdx.x * 256 + threadIdx.x;        // < 786432
    o[i] = f2bf(W[i]);
}

// Wcat1 [1536][1024]: cols 0..511 = W_hh1, cols 512..1023 = W_ih1
__global__ void cast_wcat1(const float* __restrict__ Whh, const float* __restrict__ Wih,
                           unsigned short* __restrict__ o)
{
    int i = blockIdx.x * 256 + threadIdx.x;        // < 1572864
    int row = i >> 10, c = i & 1023;
    float v = (c < 512) ? Whh[row * 512 + c] : Wih[row * 512 + (c - 512)];
    o[i] = f2bf(v);
}

__global__ void mkbias(const float* __restrict__ bih0, const float* __restrict__ bhh0,
                       const float* __restrict__ bih1, const float* __restrict__ bhh1,
                       float* __restrict__ bcomb0, float* __restrict__ bc1)
{
    int n = blockIdx.x * 256 + threadIdx.x;        // < 1536
    bcomb0[n] = bih0[n] + (n < 1024 ? bhh0[n] : 0.f);
    bc1[n]    = bih1[n] + (n < 1024 ? bhh1[n] : 0.f);
}

// ---------------------------------------------------------------------------
// Tiled f32 GEMM, bf16 TRANSPOSED write for gx0.   [verified r6-r11]
// ---------------------------------------------------------------------------
__global__ __launch_bounds__(256) void gemm_abt_t(
    const float* __restrict__ A, const float* __restrict__ B,
    const float* __restrict__ bias, unsigned short* __restrict__ C,
    int M, int N, int K)
{
    __shared__ float As[32][129];
    __shared__ float Bs[32][129];
    int m0 = blockIdx.x * 128;
    int n0 = blockIdx.y * 128;
    int tid = threadIdx.x;
    int tx = tid & 15, ty = tid >> 4;
    float acc[8][8] = {};
    for (int k0 = 0; k0 < K; k0 += 32) {
        #pragma unroll
        for (int i = 0; i < 16; i++) {
            int e = tid + i * 256;
            int row = e >> 5, col = e & 31;
            As[col][row] = A[(size_t)(m0 + row) * K + k0 + col];
            Bs[col][row] = B[(size_t)(n0 + row) * K + k0 + col];
        }
        __syncthreads();
        #pragma unroll
        for (int kk = 0; kk < 32; kk++) {
            float a[8], b[8];
            #pragma unroll
            for (int i = 0; i < 8; i++) a[i] = As[kk][ty + i * 16];
            #pragma unroll
            for (int j = 0; j < 8; j++) b[j] = Bs[kk][tx + j * 16];
            #pragma unroll
            for (int i = 0; i < 8; i++)
                #pragma unroll
                for (int j = 0; j < 8; j++) acc[i][j] += a[i] * b[j];
        }
        __syncthreads();
    }
    #pragma unroll
    for (int i = 0; i < 8; i++) {
        int m = m0 + ty + i * 16;
        int b = m / 120, t = m - b * 120;
        #pragma unroll
        for (int j = 0; j < 8; j++) {
            int n = n0 + tx + j * 16;
            C[((size_t)t * 256 + b) * G3 + n] = f2bf(acc[i][j] + bias[n]);
        }
    }
}

// ---------------------------------------------------------------------------
// XCD-partitioned persistent recurrence, MINIMAL protocol (r12):
// one monotonic counter per (layer, xcd); each WAVE publishes (+1 at AGENT
// scope after its own vmcnt(0)); every wave busy-polls the single counter
// (coalesced same-address load, no sleep, no barriers in the loop).
// Wave skew bounded to 1 step by the counter gate. h state IS the bf16 out
// buffer (fresh address every step). [data path identical to r8-r11]
// ---------------------------------------------------------------------------
__device__ __forceinline__ bool wave_wait(const int* __restrict__ cnt, int thr)
{
    for (int it = 0; it < 2000000; ++it) {
        int v = __hip_atomic_load(cnt, __ATOMIC_RELAXED, __HIP_MEMORY_SCOPE_AGENT);
        if (v >= thr) return true;
    }
    return false;   // hang guard: terminate (wrong) rather than hang
}

__global__ __launch_bounds__(256) void gru_xcd(
    const unsigned short* __restrict__ gx0,          // [120][256][1536] bf16
    const unsigned short* __restrict__ Whh0,         // [1536][512] bf16
    const unsigned short* __restrict__ Wcat1,        // [1536][1024] bf16
    const float* __restrict__ bhh0,
    const float* __restrict__ bc1,
    const float* __restrict__ bhh1,
    unsigned short* __restrict__ out0,               // [256][120][512] bf16
    unsigned short* __restrict__ out1,               // [256][120][512] bf16
    int* __restrict__ cnts,                          // [2][8] x CSTRIDE ints
    int* __restrict__ rolecnt)                       // [8] (x16 pad)
{
    __shared__ unsigned short wlds[96 * 520];        // ~97.5 KiB
    __shared__ int role_s;

    int xcd;
    asm("s_getreg_b32 %0, hwreg(20, 0, 32)" : "=s"(xcd));   // HW_REG_XCC_ID
    xcd &= 7;
    if (threadIdx.x == 0) role_s = atomicAdd(&rolecnt[xcd * 16], 1);
    __syncthreads();
    const int role = role_s;
    if (role >= 32) return;

    const int layer = role >> 4;
    const int jb    = role & 15;
    const int j0    = jb * 32;
    const int tid   = threadIdx.x;
    const int w     = tid >> 6, lane = tid & 63;
    const int l15   = lane & 15, l4 = lane >> 4;
    const int jt    = w & 1, bt = w >> 1;
    const int jloc  = jt * 16 + l15;                 // 0..31
    const int j     = j0 + jloc;
    const int bloc0 = bt * 16;                       // 0 or 16
    const int bg0   = xcd * 32;                      // global batch base

    // stage hh-part weights (96 rows x 512) into LDS, padded stride 520
    {
        const unsigned short* Wsrc = layer ? Wcat1 : Whh0;
        const int wstr = layer ? 1024 : 512;
        for (int c = tid; c < 96 * 64; c += 256) {
            int lr = c >> 6, ck = c & 63;
            int grow = (lr >> 5) * 512 + j0 + (lr & 31);
            bf16x8 v = *(const bf16x8*)(Wsrc + (size_t)grow * wstr + ck * 8);
            *(bf16x8*)&wlds[lr * 520 + ck * 8] = v;
        }
    }
    float bn_, br_ = 0.f, bz_ = 0.f, bnx_ = 0.f;
    if (layer) { br_ = bc1[j]; bz_ = bc1[512 + j]; bnx_ = bc1[1024 + j]; bn_ = bhh1[1024 + j]; }
    else       { bn_ = bhh0[1024 + j]; }
    float carry[4] = {0.f, 0.f, 0.f, 0.f};

    const int* c0 = cnts + (0 * 8 + xcd) * CSTRIDE;
    const int* c1 = cnts + (1 * 8 + xcd) * CSTRIDE;
    int* myc = cnts + ((layer * 8 + xcd)) * CSTRIDE;
    __syncthreads();                                 // weights staged

    if (!layer) {
        // ============================ layer 0 ============================
        for (int t = 0; t < T_SEQ; t++) {
            // prefetch gx0[t] (no h dependency) -- latency hides in poll
            unsigned short gr_[4], gz_[4], gn_[4];
            #pragma unroll
            for (int rr = 0; rr < 4; rr++) {
                int b = bg0 + bloc0 + 4 * l4 + rr;
                const unsigned short* gp = gx0 + ((size_t)t * 256 + b) * G3 + j;
                gr_[rr] = gp[0]; gz_[rr] = gp[512]; gn_[rr] = gp[1024];
            }
            asm volatile("" ::: "memory");           // pin prefetch issue here

            if (!wave_wait(c0, 64 * t)) break;       // all h0(t-1) published

            f32x4 a0 = {0,0,0,0}, a1 = {0,0,0,0}, a2 = {0,0,0,0};
            if (t > 0) {
                bf16x8 Areg[16];
                #pragma unroll
                for (int ks = 0; ks < 16; ks++)
                    Areg[ks] = *(const bf16x8*)(out0 + ((size_t)(bg0 + bloc0 + l15) * T_SEQ + (t - 1)) * 512 + ks * 32 + 8 * l4);
                #pragma unroll
                for (int ks = 0; ks < 16; ks++) {
                    const int ko = ks * 32 + 8 * l4;
                    bf16x8 B0 = *(const bf16x8*)&wlds[(0 * 32 + jloc) * 520 + ko];
                    bf16x8 B1 = *(const bf16x8*)&wlds[(1 * 32 + jloc) * 520 + ko];
                    bf16x8 B2 = *(const bf16x8*)&wlds[(2 * 32 + jloc) * 520 + ko];
                    a0 = __builtin_amdgcn_mfma_f32_16x16x32_bf16(Areg[ks], B0, a0, 0, 0, 0);
                    a1 = __builtin_amdgcn_mfma_f32_16x16x32_bf16(Areg[ks], B1, a1, 0, 0, 0);
                    a2 = __builtin_amdgcn_mfma_f32_16x16x32_bf16(Areg[ks], B2, a2, 0, 0, 0);
                }
            }
            #pragma unroll
            for (int rr = 0; rr < 4; rr++) {
                int b = bg0 + bloc0 + 4 * l4 + rr;
                float r = sigm_fast(bf2f(gr_[rr]) + a0[rr]);
                float z = sigm_fast(bf2f(gz_[rr]) + a1[rr]);
                float n = tanh_fast(bf2f(gn_[rr]) + r * (a2[rr] + bn_));
                float h = (1.f - z) * n + z * carry[rr];
                carry[rr] = h;
                out0[((size_t)b * T_SEQ + t) * 512 + j] = f2bf(h);
            }
            asm volatile("s_waitcnt vmcnt(0)" ::: "memory");  // own stores in L2
            if (lane == 0)
                __hip_atomic_fetch_add(myc, 1, __ATOMIC_RELAXED,
                                       __HIP_MEMORY_SCOPE_AGENT);
        }
    } else {
        // ============================ layer 1 ============================
        for (int t = 0; t < T_SEQ; t++) {
            f32x4 a0 = {0,0,0,0}, a1 = {0,0,0,0}, a2 = {0,0,0,0}, a3 = {0,0,0,0};
            // hh-part first: only needs own-layer step t-1 complete
            if (!wave_wait(c1, 64 * t)) break;
            if (t > 0) {
                bf16x8 Areg[16];
                #pragma unroll
                for (int ks = 0; ks < 16; ks++)
                    Areg[ks] = *(const bf16x8*)(out1 + ((size_t)(bg0 + bloc0 + l15) * T_SEQ + (t - 1)) * 512 + ks * 32 + 8 * l4);
                #pragma unroll
                for (int ks = 0; ks < 16; ks++) {
                    const int ko = ks * 32 + 8 * l4;
                    bf16x8 B0 = *(const bf16x8*)&wlds[(0 * 32 + jloc) * 520 + ko];
                    bf16x8 B1 = *(const bf16x8*)&wlds[(1 * 32 + jloc) * 520 + ko];
                    bf16x8 B2 = *(const bf16x8*)&wlds[(2 * 32 + jloc) * 520 + ko];
                    a0 = __builtin_amdgcn_mfma_f32_16x16x32_bf16(Areg[ks], B0, a0, 0, 0, 0);
                    a1 = __builtin_amdgcn_mfma_f32_16x16x32_bf16(Areg[ks], B1, a1, 0, 0, 0);
                    a2 = __builtin_amdgcn_mfma_f32_16x16x32_bf16(Areg[ks], B2, a2, 0, 0, 0);
                }
            }
            // x-part: needs layer0 step t complete
            if (!wave_wait(c0, 64 * (t + 1))) break;
            {
                bf16x8 Areg[16];
                #pragma unroll
                for (int ks = 0; ks < 16; ks++)
                    Areg[ks] = *(const bf16x8*)(out0 + ((size_t)(bg0 + bloc0 + l15) * T_SEQ + t) * 512 + ks * 32 + 8 * l4);
                #pragma unroll
                for (int ks = 0; ks < 16; ks++) {
                    const int ko = ks * 32 + 8 * l4;
                    const unsigned short* wb = Wcat1 + (size_t)j * 1024 + 512 + ko;
                    bf16x8 B0 = *(const bf16x8*)(wb);
                    bf16x8 B1 = *(const bf16x8*)(wb + 512 * 1024);
                    bf16x8 B2 = *(const bf16x8*)(wb + 1024 * 1024);
                    a0 = __builtin_amdgcn_mfma_f32_16x16x32_bf16(Areg[ks], B0, a0, 0, 0, 0);
                    a1 = __builtin_amdgcn_mfma_f32_16x16x32_bf16(Areg[ks], B1, a1, 0, 0, 0);
                    a3 = __builtin_amdgcn_mfma_f32_16x16x32_bf16(Areg[ks], B2, a3, 0, 0, 0);
                }
            }
            #pragma unroll
            for (int rr = 0; rr < 4; rr++) {
                int b = bg0 + bloc0 + 4 * l4 + rr;
                float r = sigm_fast(a0[rr] + br_);
                float z = sigm_fast(a1[rr] + bz_);
                float n = tanh_fast(a3[rr] + bnx_ + r * (a2[rr] + bn_));
                float h = (1.f - z) * n + z * carry[rr];
                carry[rr] = h;
                out1[((size_t)b * T_SEQ + t) * 512 + j] = f2bf(h);
            }
            asm volatile("s_waitcnt vmcnt(0)" ::: "memory");
            if (lane == 0)
                __hip_atomic_fetch_add(myc, 1, __ATOMIC_RELAXED,
                                       __HIP_MEMORY_SCOPE_AGENT);
        }
    }
}

// ---------------------------------------------------------------------------
// z partials (bf16 out reader): 960 blocks = (t, half, c-quarter).  [r8 ok]
// ---------------------------------------------------------------------------
__global__ __launch_bounds__(256) void zpart_kernel(
    const unsigned short* __restrict__ out, const float* __restrict__ Gw,
    float* __restrict__ zp)
{
    __shared__ float Os[128][33];
    __shared__ float Gs[128][33];
    int bk = blockIdx.x;
    int t = bk >> 3, half = (bk >> 2) & 1, cq = bk & 3;
    int tid = threadIdx.x;
    int tx = tid & 15, ty = tid >> 4;
    float acc[8][8] = {};
    int cbase = cq * 128;
    for (int c0 = cbase; c0 < cbase + 128; c0 += 32) {
        #pragma unroll
        for (int i = 0; i < 16; i++) {
            int e = tid + i * 256;
            int row = e >> 5, col = e & 31;
            Os[row][col] = bf2f(out[((size_t)(row + half * 128) * T_SEQ + t) * 512 + c0 + col]);
            float v = 0.f;
            if (row < 120)
                v = Gw[(size_t)row * KGATE + (size_t)t * 1024 + half * 512 + c0 + col];
            Gs[row][col] = v;
        }
        __syncthreads();
        #pragma unroll
        for (int kk = 0; kk < 32; kk++) {
            float a[8], g[8];
            #pragma unroll
            for (int i = 0; i < 8; i++) a[i] = Os[ty + i * 16][kk];
            #pragma unroll
            for (int j = 0; j < 8; j++) g[j] = Gs[tx + j * 16][kk];
            #pragma unroll
            for (int i = 0; i < 8; i++)
                #pragma unroll
                for (int j = 0; j < 8; j++) acc[i][j] += a[i] * g[j];
        }
        __syncthreads();
    }
    float* zb = zp + (size_t)bk * (128 * 120);
    #pragma unroll
    for (int i = 0; i < 8; i++) {
        int ii = ty + i * 16;
        #pragma unroll
        for (int j = 0; j < 8; j++) {
            int r = tx + j * 16;
            if (r < 120) zb[ii * 120 + r] = acc[i][j];
        }
    }
}

__global__ void zreduce(const float* __restrict__ zp,
                        const float* __restrict__ gate_b_l,
                        float* __restrict__ z)
{
    int idx = blockIdx.x * 256 + threadIdx.x;
    if (idx >= 128 * 120) return;
    float s = 0.f;
    for (int c = 0; c < 960; c++) s += zp[(size_t)c * (128 * 120) + idx];
    z[idx] = s + gate_b_l[idx % 120];
}

__global__ __launch_bounds__(128) void bn_col(
    const float* __restrict__ z, const float* __restrict__ gamma,
    const float* __restrict__ beta, float* __restrict__ wm)
{
    int r = blockIdx.x, i = threadIdx.x;
    __shared__ float sh[2];
    float v = z[i * 120 + r];
    float s = v;
    for (int o = 32; o > 0; o >>= 1) s += __shfl_down(s, o);
    if ((i & 63) == 0) sh[i >> 6] = s;
    __syncthreads();
    float m = (sh[0] + sh[1]) * (1.f / 128.f);
    __syncthreads();
    float d = (v - m) * (v - m);
    for (int o = 32; o > 0; o >>= 1) d += __shfl_down(d, o);
    if ((i & 63) == 0) sh[i >> 6] = d;
    __syncthreads();
    float var = (sh[0] + sh[1]) * (1.f / 128.f);
    float w = 1.f / (1.f + expf(-(gamma[r] * (v - m) / sqrtf(var + 1e-5f) + beta[r])));
    __syncthreads();
    float ws_ = w;
    for (int o = 32; o > 0; o >>= 1) ws_ += __shfl_down(ws_, o);
    if ((i & 63) == 0) sh[i >> 6] = ws_;
    __syncthreads();
    if (i == 0) wm[r] = (sh[0] + sh[1]) * (1.f / 128.f);
}

__global__ __launch_bounds__(128) void softmax120(
    const float* __restrict__ wm, float* __restrict__ g_out,
    float* __restrict__ g_ws)
{
    int i = threadIdx.x;
    __shared__ float sh[2];
    float v = (i < 120) ? wm[i] : -1e30f;
    float m = v;
    for (int o = 32; o > 0; o >>= 1) m = fmaxf(m, __shfl_down(m, o));
    if ((i & 63) == 0) sh[i >> 6] = m;
    __syncthreads();
    float mx = fmaxf(sh[0], sh[1]);
    float e = (i < 120) ? expf(v - mx) : 0.f;
    __syncthreads();
    float se = e;
    for (int o = 32; o > 0; o >>= 1) se += __shfl_down(se, o);
    if ((i & 63) == 0) sh[i >> 6] = se;
    __syncthreads();
    float sum = sh[0] + sh[1];
    if (i < 120) { float g = e / sum; g_out[i] = g; g_ws[i] = g; }
}

__global__ void halfmeans(const unsigned short* __restrict__ out,
                          float* __restrict__ ms, float* __restrict__ mt)
{
    int idx = blockIdx.x * 256 + threadIdx.x;
    int half = idx >= TS;
    int tc = idx - half * TS;
    const unsigned short* base = out + (size_t)(half * 128) * TS + tc;
    float s = 0.f;
    for (int i = 0; i < 128; i++) s += bf2f(base[(size_t)i * TS]);
    s *= (1.f / 128.f);
    if (half) mt[tc] = s; else ms[tc] = s;
}

__global__ __launch_bounds__(512) void transfer_part(
    const float* __restrict__ ms, const float* __restrict__ mt,
    const float* __restrict__ gw, const int* __restrict__ lenw,
    float* __restrict__ part)
{
    int t = blockIdx.x, c = threadIdx.x;
    int lw = lenw[0];
    int j0 = t - lw; if (j0 < 0) j0 = 0;
    int j1 = t + lw; if (j1 > 119) j1 = 119;
    float m_c = ms[(size_t)t * 512 + c];
    float acc = 0.f;
    for (int j = j0; j <= j1; j++) {
        float d = m_c - mt[(size_t)j * 512 + c];
        acc += d * d;
    }
    for (int o = 32; o > 0; o >>= 1) acc += __shfl_down(acc, o);
    __shared__ float sh[8];
    if ((c & 63) == 0) sh[c >> 6] = acc;
    __syncthreads();
    if (c == 0) {
        float s = 0.f;
        #pragma unroll
        for (int k = 0; k < 8; k++) s += sh[k];
        part[t] = gw[t] * s;
    }
}

__global__ __launch_bounds__(256) void yhat_kernel(
    const unsigned short* __restrict__ out1, const float* __restrict__ y,
    const float* __restrict__ fcW, const float* __restrict__ fcb,
    int dsl, float* __restrict__ dout, float* __restrict__ lp_rows)
{
    int wid = blockIdx.x * 4 + (threadIdx.x >> 6);   // 0..dsl*256-1
    int lane = threadIdx.x & 63;
    int tt = wid >> 8, b = wid & 255;
    int t = T_SEQ - dsl + tt;
    const unsigned short* row = out1 + ((size_t)b * T_SEQ + t) * 512;
    float s = 0.f;
    #pragma unroll
    for (int k = 0; k < 8; k++) s += bf2f(row[lane + 64 * k]) * fcW[lane + 64 * k];
    for (int o = 32; o > 0; o >>= 1) s += __shfl_down(s, o);
    if (lane == 0) {
        float loc = s + fcb[0];
        float sp = fmaxf(loc, 0.f) + log1pf(expf(-fabsf(loc)));
        float scale = sp + 1e-6f;
        dout[2 + tt * 256 + b] = loc;
        dout[2 + dsl * 256 + tt * 256 + b] = scale;
        float yt = y[(size_t)t * 256 + b];
        float u = (yt - loc) / scale;
        lp_rows[wid] = -0.5f * u * u - logf(scale) - 0.91893853320467274f;
    }
}

__global__ __launch_bounds__(64) void finalize(
    const float* __restrict__ lp_rows, const float* __restrict__ part0,
    const float* __restrict__ part1, float* __restrict__ dout, int n_lp)
{
    int i = threadIdx.x;
    float s = 0.f;
    for (int k = i; k < n_lp; k += 64) s += lp_rows[k];
    for (int o = 32; o > 0; o >>= 1) s += __shfl_down(s, o);
    float tr = 0.f;
    for (int k = i; k < 120; k += 64) tr += part0[k] + part1[k];
    for (int o = 32; o > 0; o >>= 1) tr += __shfl_down(tr, o);
    if (i == 0) {
        float ly = -s / (float)n_lp;
        dout[1] = ly;
        dout[0] = ly + tr;
    }
}

// ---------------------------------------------------------------------------
extern "C" void kernel_launch(void* const* d_in, const int* in_sizes, int n_in,
                              void* d_out, int out_size, void* d_ws, size_t ws_size,
                              hipStream_t stream)
{
    const float* X_cov  = (const float*)d_in[1];
    const float* X_lag  = (const float*)d_in[2];
    const float* y      = (const float*)d_in[3];
    const int*   lenw   = (const int*)d_in[5];
    const float* W_ih0  = (const float*)d_in[6];
    const float* W_hh0  = (const float*)d_in[7];
    const float* b_ih0  = (const float*)d_in[8];
    const float* b_hh0  = (const float*)d_in[9];
    const float* W_ih1  = (const float*)d_in[10];
    const float* W_hh1  = (const float*)d_in[11];
    const float* b_ih1  = (const float*)d_in[12];
    const float* b_hh1  = (const float*)d_in[13];
    const float* gate_W = (const float*)d_in[14];
    const float* gate_b = (const float*)d_in[15];
    const float* bn_g   = (const float*)d_in[16];
    const float* bn_b   = (const float*)d_in[17];
    const float* fc_W   = (const float*)d_in[18];
    const float* fc_b   = (const float*)d_in[19];
    float* dout = (float*)d_out;
    float* ws   = (float*)d_ws;

    // workspace layout (float offsets); zp aliases gx0 (dead after gru_xcd),
    // lp_rows aliases x_in (dead after gemm_abt_t)
    float* x_in    = ws;                          // 1,966,080
    unsigned short* gx0bf = (unsigned short*)(ws + 1966080);      // 47,185,920 ush
    unsigned short* out0  = (unsigned short*)(ws + 25559040);     // 15,728,640 ush
    unsigned short* out1  = (unsigned short*)(ws + 33423360);     // 15,728,640 ush
    unsigned short* Whh0bf  = (unsigned short*)(ws + 41287680);   // 786,432 ush
    unsigned short* Wcat1bf = (unsigned short*)(ws + 41680896);   // 1,572,864 ush
    float* zmat    = ws + 42467328;               // 15,360
    float* wm      = ws + 42482688;               // 120
    float* gw_ws   = ws + 42482808;               // 240
    float* msb     = ws + 42483048;               // 61,440
    float* mtb     = ws + 42544488;               // 61,440
    float* part    = ws + 42605928;               // 240
    float* bcomb0  = ws + 42606168;               // 1536
    float* bc1     = ws + 42607704;               // 1536
    int*   cnts    = (int*)(ws + 42609240);       // 16 x CSTRIDE ints
    int*   rolecnt = (int*)(ws + 42613336);       // 128 ints
    float* zp      = ws + 1966080;                // alias of gx0 region
    float* lp_rows = x_in;                        // alias

    int dsl = (out_size - 2 - 2 * T_SEQ) / (2 * BATCH);   // = 24

    build_x<<<dim3(7680), 256, 0, stream>>>(X_lag, X_cov, x_in);
    cast_whh0<<<dim3(3072), 256, 0, stream>>>(W_hh0, Whh0bf);
    cast_wcat1<<<dim3(6144), 256, 0, stream>>>(W_hh1, W_ih1, Wcat1bf);
    mkbias<<<dim3(6), 256, 0, stream>>>(b_ih0, b_hh0, b_ih1, b_hh1, bcomb0, bc1);
    hipMemsetAsync(cnts, 0, 16 * CSTRIDE * sizeof(int), stream);   // counters = 0
    hipMemsetAsync(rolecnt, 0, 128 * sizeof(int), stream);

    gemm_abt_t<<<dim3(240, 12), 256, 0, stream>>>(x_in, W_ih0, bcomb0, gx0bf,
                                                  MROWS, G3, 64);

    gru_xcd<<<dim3(320), 256, 0, stream>>>(gx0bf, Whh0bf, Wcat1bf,
                                           b_hh0, bc1, b_hh1,
                                           out0, out1, cnts, rolecnt);

    for (int l = 0; l < 2; l++) {
        const unsigned short* o = l ? out1 : out0;
        zpart_kernel<<<960, 256, 0, stream>>>(o, gate_W + (size_t)l * 120 * KGATE, zp);
        zreduce<<<60, 256, 0, stream>>>(zp, gate_b + l * 120, zmat);
        bn_col<<<120, 128, 0, stream>>>(zmat, bn_g + l * 120, bn_b + l * 120, wm);
        softmax120<<<1, 128, 0, stream>>>(wm, dout + 2 + 2 * dsl * 256 + l * 120,
                                          gw_ws + l * 120);
        halfmeans<<<480, 256, 0, stream>>>(o, msb, mtb);
        transfer_part<<<120, 512, 0, stream>>>(msb, mtb, gw_ws + l * 120, lenw,
                                               part + l * 120);
    }

    yhat_kernel<<<dsl * 64, 256, 0, stream>>>(out1, y, fc_W, fc_b, dsl, dout, lp_rows);
    finalize<<<1, 64, 0, stream>>>(lp_rows, part, part + 120, dout, dsl * 256);
}

// Round 13
// 2058.012 us; speedup vs baseline: 1.0119x; 1.0119x over previous
//
#include <hip/hip_runtime.h>
#include <math.h>

#define T_SEQ 120
#define BATCH 256
#define HID   512
#define G3    1536            // 3*HID
#define MROWS (BATCH*T_SEQ)   // 30720
#define TS    (T_SEQ*HID)     // 61440, row stride per batch in out buffers
#define KGATE 122880          // T_SEQ*2*HID
#define FSTRIDE 16            // flag stride (ints) -> one flag per 64B line

typedef __attribute__((ext_vector_type(8))) short bf16x8;
typedef __attribute__((ext_vector_type(4))) float f32x4;

__device__ __forceinline__ unsigned short f2bf(float f) {
    union { float f; unsigned u; } x; x.f = f;
    unsigned r = x.u + 0x7fffu + ((x.u >> 16) & 1u);   // RNE
    return (unsigned short)(r >> 16);
}
__device__ __forceinline__ float bf2f(unsigned short u) {
    union { unsigned u; float f; } x; x.u = ((unsigned)u) << 16; return x.f;
}
__device__ __forceinline__ float sigm_fast(float x) {
    return 1.f / (1.f + __expf(-x));
}
__device__ __forceinline__ float tanh_fast(float x) {
    float e = __expf(2.f * x);
    return 1.f - 2.f / (e + 1.f);
}

// ---------------------------------------------------------------------------
__global__ void build_x(const float* __restrict__ X_lag,
                        const float* __restrict__ X_cov,
                        float* __restrict__ x_in)
{
    int idx = blockIdx.x * 256 + threadIdx.x;      // < 30720*64
    int d = idx & 63;
    int m = idx >> 6;                               // b*120 + t
    int b = m / 120, t = m - b * 120;
    float v;
    if (d < 32) v = X_lag[((size_t)t * BATCH + b) * 32 + d];
    else        v = X_cov[((size_t)t * BATCH + b) * 32 + (d - 32)];
    x_in[idx] = v;
}

__global__ void cast_whh0(const float* __restrict__ W, unsigned short* __restrict__ o)
{
    int i = blockIdx.x * 256 + threadIdx.x;        // < 786432
    o[i] = f2bf(W[i]);
}

// Wcat1 [1536][1024]: cols 0..511 = W_hh1, cols 512..1023 = W_ih1
__global__ void cast_wcat1(const float* __restrict__ Whh, const float* __restrict__ Wih,
                           unsigned short* __restrict__ o)
{
    int i = blockIdx.x * 256 + threadIdx.x;        // < 1572864
    int row = i >> 10, c = i & 1023;
    float v = (c < 512) ? Whh[row * 512 + c] : Wih[row * 512 + (c - 512)];
    o[i] = f2bf(v);
}

__global__ void mkbias(const float* __restrict__ bih0, const float* __restrict__ bhh0,
                       const float* __restrict__ bih1, const float* __restrict__ bhh1,
                       float* __restrict__ bcomb0, float* __restrict__ bc1)
{
    int n = blockIdx.x * 256 + threadIdx.x;        // < 1536
    bcomb0[n] = bih0[n] + (n < 1024 ? bhh0[n] : 0.f);
    bc1[n]    = bih1[n] + (n < 1024 ? bhh1[n] : 0.f);
}

// ---------------------------------------------------------------------------
// Tiled f32 GEMM, bf16 TRANSPOSED write for gx0.   [verified r6-r12]
// ---------------------------------------------------------------------------
__global__ __launch_bounds__(256) void gemm_abt_t(
    const float* __restrict__ A, const float* __restrict__ B,
    const float* __restrict__ bias, unsigned short* __restrict__ C,
    int M, int N, int K)
{
    __shared__ float As[32][129];
    __shared__ float Bs[32][129];
    int m0 = blockIdx.x * 128;
    int n0 = blockIdx.y * 128;
    int tid = threadIdx.x;
    int tx = tid & 15, ty = tid >> 4;
    float acc[8][8] = {};
    for (int k0 = 0; k0 < K; k0 += 32) {
        #pragma unroll
        for (int i = 0; i < 16; i++) {
            int e = tid + i * 256;
            int row = e >> 5, col = e & 31;
            As[col][row] = A[(size_t)(m0 + row) * K + k0 + col];
            Bs[col][row] = B[(size_t)(n0 + row) * K + k0 + col];
        }
        __syncthreads();
        #pragma unroll
        for (int kk = 0; kk < 32; kk++) {
            float a[8], b[8];
            #pragma unroll
            for (int i = 0; i < 8; i++) a[i] = As[kk][ty + i * 16];
            #pragma unroll
            for (int j = 0; j < 8; j++) b[j] = Bs[kk][tx + j * 16];
            #pragma unroll
            for (int i = 0; i < 8; i++)
                #pragma unroll
                for (int j = 0; j < 8; j++) acc[i][j] += a[i] * b[j];
        }
        __syncthreads();
    }
    #pragma unroll
    for (int i = 0; i < 8; i++) {
        int m = m0 + ty + i * 16;
        int b = m / 120, t = m - b * 120;
        #pragma unroll
        for (int j = 0; j < 8; j++) {
            int n = n0 + tx + j * 16;
            C[((size_t)t * 256 + b) * G3 + n] = f2bf(acc[i][j] + bias[n]);
        }
    }
}

// ---------------------------------------------------------------------------
// XCD-partitioned persistent recurrence (r13): per-WAVE flag lines.
// Each physical XCD (HW_REG_XCC_ID) owns batches [xcd*32, xcd*32+32).
// 32 resident blocks/XCD claim roles via atomicAdd: 0-15 layer0 j-blocks
// (32 cols each), 16-31 layer1. h state IS the bf16 out buffer (fresh
// address every step -> no stale cached line). Data: plain stores + per-wave
// vmcnt(0). Flags: ONE LINE PER WAVE (64/layer/XCD), parallel AGENT stores
// (no RMW serialization), gang-poll: 64 lanes watch 64 lines, one round trip
// per poll, no sleep, no __syncthreads in the loop (wave skew bounded by
// flag gates; LDS weights read-only after staging; carries per-thread).
// ---------------------------------------------------------------------------
__device__ __forceinline__ bool wait64(const int* __restrict__ base, int thr,
                                       int lane)
{
    const int* ap = base + lane * FSTRIDE;
    for (int it = 0; it < 2000000; ++it) {
        int v = __hip_atomic_load(ap, __ATOMIC_RELAXED, __HIP_MEMORY_SCOPE_AGENT);
        if (__all(v >= thr)) return true;
    }
    return false;   // hang guard: terminate (wrong) rather than hang
}
__device__ __forceinline__ bool wait64x2(const int* __restrict__ b0, int thr0,
                                         const int* __restrict__ b1, int thr1,
                                         int lane)
{
    const int* a0 = b0 + lane * FSTRIDE;
    const int* a1 = b1 + lane * FSTRIDE;
    for (int it = 0; it < 2000000; ++it) {
        int v0 = __hip_atomic_load(a0, __ATOMIC_RELAXED, __HIP_MEMORY_SCOPE_AGENT);
        int v1 = __hip_atomic_load(a1, __ATOMIC_RELAXED, __HIP_MEMORY_SCOPE_AGENT);
        bool ok0 = __all(v0 >= thr0);
        bool ok1 = __all(v1 >= thr1);
        if (ok0 && ok1) return true;
    }
    return false;
}

__global__ __launch_bounds__(256) void gru_xcd(
    const unsigned short* __restrict__ gx0,          // [120][256][1536] bf16
    const unsigned short* __restrict__ Whh0,         // [1536][512] bf16
    const unsigned short* __restrict__ Wcat1,        // [1536][1024] bf16
    const float* __restrict__ bhh0,
    const float* __restrict__ bc1,
    const float* __restrict__ bhh1,
    unsigned short* __restrict__ out0,               // [256][120][512] bf16
    unsigned short* __restrict__ out1,               // [256][120][512] bf16
    int* __restrict__ flags,                         // [2][8][64] x FSTRIDE
    int* __restrict__ rolecnt)                       // [8] (x16 pad)
{
    __shared__ unsigned short wlds[96 * 520];        // ~97.5 KiB
    __shared__ int role_s;

    int xcd;
    asm("s_getreg_b32 %0, hwreg(20, 0, 32)" : "=s"(xcd));   // HW_REG_XCC_ID
    xcd &= 7;
    if (threadIdx.x == 0) role_s = atomicAdd(&rolecnt[xcd * 16], 1);
    __syncthreads();
    const int role = role_s;
    if (role >= 32) return;

    const int layer = role >> 4;
    const int jb    = role & 15;
    const int j0    = jb * 32;
    const int tid   = threadIdx.x;
    const int w     = tid >> 6, lane = tid & 63;
    const int l15   = lane & 15, l4 = lane >> 4;
    const int jt    = w & 1, bt = w >> 1;
    const int jloc  = jt * 16 + l15;                 // 0..31
    const int j     = j0 + jloc;
    const int bloc0 = bt * 16;                       // 0 or 16
    const int bg0   = xcd * 32;                      // global batch base

    // stage hh-part weights (96 rows x 512) into LDS, padded stride 520
    {
        const unsigned short* Wsrc = layer ? Wcat1 : Whh0;
        const int wstr = layer ? 1024 : 512;
        for (int c = tid; c < 96 * 64; c += 256) {
            int lr = c >> 6, ck = c & 63;
            int grow = (lr >> 5) * 512 + j0 + (lr & 31);
            bf16x8 v = *(const bf16x8*)(Wsrc + (size_t)grow * wstr + ck * 8);
            *(bf16x8*)&wlds[lr * 520 + ck * 8] = v;
        }
    }
    float bn_, br_ = 0.f, bz_ = 0.f, bnx_ = 0.f;
    if (layer) { br_ = bc1[j]; bz_ = bc1[512 + j]; bnx_ = bc1[1024 + j]; bn_ = bhh1[1024 + j]; }
    else       { bn_ = bhh0[1024 + j]; }
    float carry[4] = {0.f, 0.f, 0.f, 0.f};

    const int* f0b = flags + (0 * 8 + xcd) * 64 * FSTRIDE;
    const int* f1b = flags + (1 * 8 + xcd) * 64 * FSTRIDE;
    int* myf = flags + ((layer * 8 + xcd) * 64 + (jb * 4 + w)) * FSTRIDE;
    __syncthreads();                                 // weights staged

    if (!layer) {
        // ============================ layer 0 ============================
        for (int t = 0; t < T_SEQ; t++) {
            // prefetch gx0[t] (no h dependency) -- drains in first poll iter
            unsigned short gr_[4], gz_[4], gn_[4];
            #pragma unroll
            for (int rr = 0; rr < 4; rr++) {
                int b = bg0 + bloc0 + 4 * l4 + rr;
                const unsigned short* gp = gx0 + ((size_t)t * 256 + b) * G3 + j;
                gr_[rr] = gp[0]; gz_[rr] = gp[512]; gn_[rr] = gp[1024];
            }
            asm volatile("" ::: "memory");           // pin prefetch issue here

            if (!wait64(f0b, t - 1, lane)) break;    // all 64 L0 waves done t-1

            f32x4 a0 = {0,0,0,0}, a1 = {0,0,0,0}, a2 = {0,0,0,0};
            if (t > 0) {
                bf16x8 Areg[16];
                #pragma unroll
                for (int ks = 0; ks < 16; ks++)
                    Areg[ks] = *(const bf16x8*)(out0 + ((size_t)(bg0 + bloc0 + l15) * T_SEQ + (t - 1)) * 512 + ks * 32 + 8 * l4);
                #pragma unroll
                for (int ks = 0; ks < 16; ks++) {
                    const int ko = ks * 32 + 8 * l4;
                    bf16x8 B0 = *(const bf16x8*)&wlds[(0 * 32 + jloc) * 520 + ko];
                    bf16x8 B1 = *(const bf16x8*)&wlds[(1 * 32 + jloc) * 520 + ko];
                    bf16x8 B2 = *(const bf16x8*)&wlds[(2 * 32 + jloc) * 520 + ko];
                    a0 = __builtin_amdgcn_mfma_f32_16x16x32_bf16(Areg[ks], B0, a0, 0, 0, 0);
                    a1 = __builtin_amdgcn_mfma_f32_16x16x32_bf16(Areg[ks], B1, a1, 0, 0, 0);
                    a2 = __builtin_amdgcn_mfma_f32_16x16x32_bf16(Areg[ks], B2, a2, 0, 0, 0);
                }
            }
            #pragma unroll
            for (int rr = 0; rr < 4; rr++) {
                int b = bg0 + bloc0 + 4 * l4 + rr;
                float r = sigm_fast(bf2f(gr_[rr]) + a0[rr]);
                float z = sigm_fast(bf2f(gz_[rr]) + a1[rr]);
                float n = tanh_fast(bf2f(gn_[rr]) + r * (a2[rr] + bn_));
                float h = (1.f - z) * n + z * carry[rr];
                carry[rr] = h;
                out0[((size_t)b * T_SEQ + t) * 512 + j] = f2bf(h);
            }
            asm volatile("s_waitcnt vmcnt(0)" ::: "memory");  // own stores in L2
            if (lane == 0)
                __hip_atomic_store(myf, t, __ATOMIC_RELAXED, __HIP_MEMORY_SCOPE_AGENT);
        }
    } else {
        // ============================ layer 1 ============================
        for (int t = 0; t < T_SEQ; t++) {
            // single merged wait: own layer done t-1 AND layer0 done t
            if (!wait64x2(f1b, t - 1, f0b, t, lane)) break;

            f32x4 a0 = {0,0,0,0}, a1 = {0,0,0,0}, a2 = {0,0,0,0}, a3 = {0,0,0,0};
            if (t > 0) {
                bf16x8 Areg[16];
                #pragma unroll
                for (int ks = 0; ks < 16; ks++)
                    Areg[ks] = *(const bf16x8*)(out1 + ((size_t)(bg0 + bloc0 + l15) * T_SEQ + (t - 1)) * 512 + ks * 32 + 8 * l4);
                #pragma unroll
                for (int ks = 0; ks < 16; ks++) {
                    const int ko = ks * 32 + 8 * l4;
                    bf16x8 B0 = *(const bf16x8*)&wlds[(0 * 32 + jloc) * 520 + ko];
                    bf16x8 B1 = *(const bf16x8*)&wlds[(1 * 32 + jloc) * 520 + ko];
                    bf16x8 B2 = *(const bf16x8*)&wlds[(2 * 32 + jloc) * 520 + ko];
                    a0 = __builtin_amdgcn_mfma_f32_16x16x32_bf16(Areg[ks], B0, a0, 0, 0, 0);
                    a1 = __builtin_amdgcn_mfma_f32_16x16x32_bf16(Areg[ks], B1, a1, 0, 0, 0);
                    a2 = __builtin_amdgcn_mfma_f32_16x16x32_bf16(Areg[ks], B2, a2, 0, 0, 0);
                }
            }
            {
                bf16x8 Areg[16];
                #pragma unroll
                for (int ks = 0; ks < 16; ks++)
                    Areg[ks] = *(const bf16x8*)(out0 + ((size_t)(bg0 + bloc0 + l15) * T_SEQ + t) * 512 + ks * 32 + 8 * l4);
                #pragma unroll
                for (int ks = 0; ks < 16; ks++) {
                    const int ko = ks * 32 + 8 * l4;
                    const unsigned short* wb = Wcat1 + (size_t)j * 1024 + 512 + ko;
                    bf16x8 B0 = *(const bf16x8*)(wb);
                    bf16x8 B1 = *(const bf16x8*)(wb + 512 * 1024);
                    bf16x8 B2 = *(const bf16x8*)(wb + 1024 * 1024);
                    a0 = __builtin_amdgcn_mfma_f32_16x16x32_bf16(Areg[ks], B0, a0, 0, 0, 0);
                    a1 = __builtin_amdgcn_mfma_f32_16x16x32_bf16(Areg[ks], B1, a1, 0, 0, 0);
                    a3 = __builtin_amdgcn_mfma_f32_16x16x32_bf16(Areg[ks], B2, a3, 0, 0, 0);
                }
            }
            #pragma unroll
            for (int rr = 0; rr < 4; rr++) {
                int b = bg0 + bloc0 + 4 * l4 + rr;
                float r = sigm_fast(a0[rr] + br_);
                float z = sigm_fast(a1[rr] + bz_);
                float n = tanh_fast(a3[rr] + bnx_ + r * (a2[rr] + bn_));
                float h = (1.f - z) * n + z * carry[rr];
                carry[rr] = h;
                out1[((size_t)b * T_SEQ + t) * 512 + j] = f2bf(h);
            }
            asm volatile("s_waitcnt vmcnt(0)" ::: "memory");
            if (lane == 0)
                __hip_atomic_store(myf, t, __ATOMIC_RELAXED, __HIP_MEMORY_SCOPE_AGENT);
        }
    }
}

// ---------------------------------------------------------------------------
// z partials (bf16 out reader): 960 blocks = (t, half, c-quarter).  [r8 ok]
// ---------------------------------------------------------------------------
__global__ __launch_bounds__(256) void zpart_kernel(
    const unsigned short* __restrict__ out, const float* __restrict__ Gw,
    float* __restrict__ zp)
{
    __shared__ float Os[128][33];
    __shared__ float Gs[128][33];
    int bk = blockIdx.x;
    int t = bk >> 3, half = (bk >> 2) & 1, cq = bk & 3;
    int tid = threadIdx.x;
    int tx = tid & 15, ty = tid >> 4;
    float acc[8][8] = {};
    int cbase = cq * 128;
    for (int c0 = cbase; c0 < cbase + 128; c0 += 32) {
        #pragma unroll
        for (int i = 0; i < 16; i++) {
            int e = tid + i * 256;
            int row = e >> 5, col = e & 31;
            Os[row][col] = bf2f(out[((size_t)(row + half * 128) * T_SEQ + t) * 512 + c0 + col]);
            float v = 0.f;
            if (row < 120)
                v = Gw[(size_t)row * KGATE + (size_t)t * 1024 + half * 512 + c0 + col];
            Gs[row][col] = v;
        }
        __syncthreads();
        #pragma unroll
        for (int kk = 0; kk < 32; kk++) {
            float a[8], g[8];
            #pragma unroll
            for (int i = 0; i < 8; i++) a[i] = Os[ty + i * 16][kk];
            #pragma unroll
            for (int j = 0; j < 8; j++) g[j] = Gs[tx + j * 16][kk];
            #pragma unroll
            for (int i = 0; i < 8; i++)
                #pragma unroll
                for (int j = 0; j < 8; j++) acc[i][j] += a[i] * g[j];
        }
        __syncthreads();
    }
    float* zb = zp + (size_t)bk * (128 * 120);
    #pragma unroll
    for (int i = 0; i < 8; i++) {
        int ii = ty + i * 16;
        #pragma unroll
        for (int j = 0; j < 8; j++) {
            int r = tx + j * 16;
            if (r < 120) zb[ii * 120 + r] = acc[i][j];
        }
    }
}

__global__ void zreduce(const float* __restrict__ zp,
                        const float* __restrict__ gate_b_l,
                        float* __restrict__ z)
{
    int idx = blockIdx.x * 256 + threadIdx.x;
    if (idx >= 128 * 120) return;
    float s = 0.f;
    for (int c = 0; c < 960; c++) s += zp[(size_t)c * (128 * 120) + idx];
    z[idx] = s + gate_b_l[idx % 120];
}

__global__ __launch_bounds__(128) void bn_col(
    const float* __restrict__ z, const float* __restrict__ gamma,
    const float* __restrict__ beta, float* __restrict__ wm)
{
    int r = blockIdx.x, i = threadIdx.x;
    __shared__ float sh[2];
    float v = z[i * 120 + r];
    float s = v;
    for (int o = 32; o > 0; o >>= 1) s += __shfl_down(s, o);
    if ((i & 63) == 0) sh[i >> 6] = s;
    __syncthreads();
    float m = (sh[0] + sh[1]) * (1.f / 128.f);
    __syncthreads();
    float d = (v - m) * (v - m);
    for (int o = 32; o > 0; o >>= 1) d += __shfl_down(d, o);
    if ((i & 63) == 0) sh[i >> 6] = d;
    __syncthreads();
    float var = (sh[0] + sh[1]) * (1.f / 128.f);
    float w = 1.f / (1.f + expf(-(gamma[r] * (v - m) / sqrtf(var + 1e-5f) + beta[r])));
    __syncthreads();
    float ws_ = w;
    for (int o = 32; o > 0; o >>= 1) ws_ += __shfl_down(ws_, o);
    if ((i & 63) == 0) sh[i >> 6] = ws_;
    __syncthreads();
    if (i == 0) wm[r] = (sh[0] + sh[1]) * (1.f / 128.f);
}

__global__ __launch_bounds__(128) void softmax120(
    const float* __restrict__ wm, float* __restrict__ g_out,
    float* __restrict__ g_ws)
{
    int i = threadIdx.x;
    __shared__ float sh[2];
    float v = (i < 120) ? wm[i] : -1e30f;
    float m = v;
    for (int o = 32; o > 0; o >>= 1) m = fmaxf(m, __shfl_down(m, o));
    if ((i & 63) == 0) sh[i >> 6] = m;
    __syncthreads();
    float mx = fmaxf(sh[0], sh[1]);
    float e = (i < 120) ? expf(v - mx) : 0.f;
    __syncthreads();
    float se = e;
    for (int o = 32; o > 0; o >>= 1) se += __shfl_down(se, o);
    if ((i & 63) == 0) sh[i >> 6] = se;
    __syncthreads();
    float sum = sh[0] + sh[1];
    if (i < 120) { float g = e / sum; g_out[i] = g; g_ws[i] = g; }
}

__global__ void halfmeans(const unsigned short* __restrict__ out,
                          float* __restrict__ ms, float* __restrict__ mt)
{
    int idx = blockIdx.x * 256 + threadIdx.x;
    int half = idx >= TS;
    int tc = idx - half * TS;
    const unsigned short* base = out + (size_t)(half * 128) * TS + tc;
    float s = 0.f;
    for (int i = 0; i < 128; i++) s += bf2f(base[(size_t)i * TS]);
    s *= (1.f / 128.f);
    if (half) mt[tc] = s; else ms[tc] = s;
}

__global__ __launch_bounds__(512) void transfer_part(
    const float* __restrict__ ms, const float* __restrict__ mt,
    const float* __restrict__ gw, const int* __restrict__ lenw,
    float* __restrict__ part)
{
    int t = blockIdx.x, c = threadIdx.x;
    int lw = lenw[0];
    int j0 = t - lw; if (j0 < 0) j0 = 0;
    int j1 = t + lw; if (j1 > 119) j1 = 119;
    float m_c = ms[(size_t)t * 512 + c];
    float acc = 0.f;
    for (int j = j0; j <= j1; j++) {
        float d = m_c - mt[(size_t)j * 512 + c];
        acc += d * d;
    }
    for (int o = 32; o > 0; o >>= 1) acc += __shfl_down(acc, o);
    __shared__ float sh[8];
    if ((c & 63) == 0) sh[c >> 6] = acc;
    __syncthreads();
    if (c == 0) {
        float s = 0.f;
        #pragma unroll
        for (int k = 0; k < 8; k++) s += sh[k];
        part[t] = gw[t] * s;
    }
}

__global__ __launch_bounds__(256) void yhat_kernel(
    const unsigned short* __restrict__ out1, const float* __restrict__ y,
    const float* __restrict__ fcW, const float* __restrict__ fcb,
    int dsl, float* __restrict__ dout, float* __restrict__ lp_rows)
{
    int wid = blockIdx.x * 4 + (threadIdx.x >> 6);   // 0..dsl*256-1
    int lane = threadIdx.x & 63;
    int tt = wid >> 8, b = wid & 255;
    int t = T_SEQ - dsl + tt;
    const unsigned short* row = out1 + ((size_t)b * T_SEQ + t) * 512;
    float s = 0.f;
    #pragma unroll
    for (int k = 0; k < 8; k++) s += bf2f(row[lane + 64 * k]) * fcW[lane + 64 * k];
    for (int o = 32; o > 0; o >>= 1) s += __shfl_down(s, o);
    if (lane == 0) {
        float loc = s + fcb[0];
        float sp = fmaxf(loc, 0.f) + log1pf(expf(-fabsf(loc)));
        float scale = sp + 1e-6f;
        dout[2 + tt * 256 + b] = loc;
        dout[2 + dsl * 256 + tt * 256 + b] = scale;
        float yt = y[(size_t)t * 256 + b];
        float u = (yt - loc) / scale;
        lp_rows[wid] = -0.5f * u * u - logf(scale) - 0.91893853320467274f;
    }
}

__global__ __launch_bounds__(64) void finalize(
    const float* __restrict__ lp_rows, const float* __restrict__ part0,
    const float* __restrict__ part1, float* __restrict__ dout, int n_lp)
{
    int i = threadIdx.x;
    float s = 0.f;
    for (int k = i; k < n_lp; k += 64) s += lp_rows[k];
    for (int o = 32; o > 0; o >>= 1) s += __shfl_down(s, o);
    float tr = 0.f;
    for (int k = i; k < 120; k += 64) tr += part0[k] + part1[k];
    for (int o = 32; o > 0; o >>= 1) tr += __shfl_down(tr, o);
    if (i == 0) {
        float ly = -s / (float)n_lp;
        dout[1] = ly;
        dout[0] = ly + tr;
    }
}

// ---------------------------------------------------------------------------
extern "C" void kernel_launch(void* const* d_in, const int* in_sizes, int n_in,
                              void* d_out, int out_size, void* d_ws, size_t ws_size,
                              hipStream_t stream)
{
    const float* X_cov  = (const float*)d_in[1];
    const float* X_lag  = (const float*)d_in[2];
    const float* y      = (const float*)d_in[3];
    const int*   lenw   = (const int*)d_in[5];
    const float* W_ih0  = (const float*)d_in[6];
    const float* W_hh0  = (const float*)d_in[7];
    const float* b_ih0  = (const float*)d_in[8];
    const float* b_hh0  = (const float*)d_in[9];
    const float* W_ih1  = (const float*)d_in[10];
    const float* W_hh1  = (const float*)d_in[11];
    const float* b_ih1  = (const float*)d_in[12];
    const float* b_hh1  = (const float*)d_in[13];
    const float* gate_W = (const float*)d_in[14];
    const float* gate_b = (const float*)d_in[15];
    const float* bn_g   = (const float*)d_in[16];
    const float* bn_b   = (const float*)d_in[17];
    const float* fc_W   = (const float*)d_in[18];
    const float* fc_b   = (const float*)d_in[19];
    float* dout = (float*)d_out;
    float* ws   = (float*)d_ws;

    // workspace layout (float offsets); zp aliases gx0 (dead after gru_xcd),
    // lp_rows aliases x_in (dead after gemm_abt_t)
    float* x_in    = ws;                          // 1,966,080
    unsigned short* gx0bf = (unsigned short*)(ws + 1966080);      // 47,185,920 ush
    unsigned short* out0  = (unsigned short*)(ws + 25559040);     // 15,728,640 ush
    unsigned short* out1  = (unsigned short*)(ws + 33423360);     // 15,728,640 ush
    unsigned short* Whh0bf  = (unsigned short*)(ws + 41287680);   // 786,432 ush
    unsigned short* Wcat1bf = (unsigned short*)(ws + 41680896);   // 1,572,864 ush
    float* zmat    = ws + 42467328;               // 15,360
    float* wm      = ws + 42482688;               // 120
    float* gw_ws   = ws + 42482808;               // 240
    float* msb     = ws + 42483048;               // 61,440
    float* mtb     = ws + 42544488;               // 61,440
    float* part    = ws + 42605928;               // 240
    float* bcomb0  = ws + 42606168;               // 1536
    float* bc1     = ws + 42607704;               // 1536
    int*   flags   = (int*)(ws + 42609240);       // 16384 ints (1024 lines)
    int*   rolecnt = (int*)(ws + 42625624);       // 128 ints
    float* zp      = ws + 1966080;                // alias of gx0 region
    float* lp_rows = x_in;                        // alias

    int dsl = (out_size - 2 - 2 * T_SEQ) / (2 * BATCH);   // = 24

    build_x<<<dim3(7680), 256, 0, stream>>>(X_lag, X_cov, x_in);
    cast_whh0<<<dim3(3072), 256, 0, stream>>>(W_hh0, Whh0bf);
    cast_wcat1<<<dim3(6144), 256, 0, stream>>>(W_hh1, W_ih1, Wcat1bf);
    mkbias<<<dim3(6), 256, 0, stream>>>(b_ih0, b_hh0, b_ih1, b_hh1, bcomb0, bc1);
    hipMemsetAsync(flags, 0xFF, 16384 * sizeof(int), stream);   // flags = -1
    hipMemsetAsync(rolecnt, 0, 128 * sizeof(int), stream);

    gemm_abt_t<<<dim3(240, 12), 256, 0, stream>>>(x_in, W_ih0, bcomb0, gx0bf,
                                                  MROWS, G3, 64);

    gru_xcd<<<dim3(320), 256, 0, stream>>>(gx0bf, Whh0bf, Wcat1bf,
                                           b_hh0, bc1, b_hh1,
                                           out0, out1, flags, rolecnt);

    for (int l = 0; l < 2; l++) {
        const unsigned short* o = l ? out1 : out0;
        zpart_kernel<<<960, 256, 0, stream>>>(o, gate_W + (size_t)l * 120 * KGATE, zp);
        zreduce<<<60, 256, 0, stream>>>(zp, gate_b + l * 120, zmat);
        bn_col<<<120, 128, 0, stream>>>(zmat, bn_g + l * 120, bn_b + l * 120, wm);
        softmax120<<<1, 128, 0, stream>>>(wm, dout + 2 + 2 * dsl * 256 + l * 120,
                                          gw_ws + l * 120);
        halfmeans<<<480, 256, 0, stream>>>(o, msb, mtb);
        transfer_part<<<120, 512, 0, stream>>>(msb, mtb, gw_ws + l * 120, lenw,
                                               part + l * 120);
    }

    yhat_kernel<<<dsl * 64, 256, 0, stream>>>(out1, y, fc_W, fc_b, dsl, dout, lp_rows);
    finalize<<<1, 64, 0, stream>>>(lp_rows, part, part + 120, dout, dsl * 256);
}

// Round 14
// 1838.544 us; speedup vs baseline: 1.1327x; 1.1194x over previous
//
#include <hip/hip_runtime.h>
#include <math.h>

#define T_SEQ 120
#define BATCH 256
#define HID   512
#define G3    1536            // 3*HID
#define TS    (T_SEQ*HID)     // 61440
#define KGATE 122880          // T_SEQ*2*HID
#define FSTRIDE 16            // flag stride (ints) -> one flag per 64B line

typedef __attribute__((ext_vector_type(8))) short bf16x8;
typedef __attribute__((ext_vector_type(4))) float f32x4;

__device__ __forceinline__ unsigned short f2bf(float f) {
    union { float f; unsigned u; } x; x.f = f;
    unsigned r = x.u + 0x7fffu + ((x.u >> 16) & 1u);   // RNE
    return (unsigned short)(r >> 16);
}
__device__ __forceinline__ float bf2f(unsigned short u) {
    union { unsigned u; float f; } x; x.u = ((unsigned)u) << 16; return x.f;
}
__device__ __forceinline__ float sigm_fast(float x) {
    return 1.f / (1.f + __expf(-x));
}
__device__ __forceinline__ float tanh_fast(float x) {
    float e = __expf(2.f * x);
    return 1.f - 2.f / (e + 1.f);
}

// ---------------------------------------------------------------------------
__global__ void cast_whh0(const float* __restrict__ W, unsigned short* __restrict__ o)
{
    int i = blockIdx.x * 256 + threadIdx.x;        // < 786432
    o[i] = f2bf(W[i]);
}

// Wcat1 [1536][1024]: cols 0..511 = W_hh1, cols 512..1023 = W_ih1
__global__ void cast_wcat1(const float* __restrict__ Whh, const float* __restrict__ Wih,
                           unsigned short* __restrict__ o)
{
    int i = blockIdx.x * 256 + threadIdx.x;        // < 1572864
    int row = i >> 10, c = i & 1023;
    float v = (c < 512) ? Whh[row * 512 + c] : Wih[row * 512 + (c - 512)];
    o[i] = f2bf(v);
}

__global__ void mkbias(const float* __restrict__ bih0, const float* __restrict__ bhh0,
                       const float* __restrict__ bih1, const float* __restrict__ bhh1,
                       float* __restrict__ bcomb0, float* __restrict__ bc1)
{
    int n = blockIdx.x * 256 + threadIdx.x;        // < 1536
    bcomb0[n] = bih0[n] + (n < 1024 ? bhh0[n] : 0.f);
    bc1[n]    = bih1[n] + (n < 1024 ? bhh1[n] : 0.f);
}

// ---------------------------------------------------------------------------
// XCD-partitioned persistent recurrence: r10's PROVEN protocol, with the
// gx input GEMM fused into layer-0 blocks (computed in the poll shadow,
// f32, Wih slice in LDS) and a DVFS-buster FMA chain in the poll loops.
// Each physical XCD (HW_REG_XCC_ID) owns batches [xcd*32, xcd*32+32).
// 32 resident blocks/XCD claim roles via atomicAdd: 0-15 layer0 j-blocks,
// 16-31 layer1. h state IS the bf16 out buffer (fresh address every step).
// Data: plain stores + vmcnt(0); flags: AGENT atomics (r8-proven).
// ---------------------------------------------------------------------------
__device__ __forceinline__ bool wait16(const int* __restrict__ fb, int thr, int lane)
{
    const int* ap = fb + (lane & 15) * FSTRIDE;
    float x0 = (float)lane, x1 = x0 + 1.f, x2 = x0 + 2.f, x3 = x0 + 3.f;
    for (int it = 0; it < 300000; ++it) {
        int v = __hip_atomic_load(ap, __ATOMIC_RELAXED, __HIP_MEMORY_SCOPE_AGENT);
        if (__all(v >= thr)) {
            asm volatile("" :: "v"(x0), "v"(x1), "v"(x2), "v"(x3));
            return true;
        }
        #pragma unroll
        for (int q = 0; q < 12; q++) {          // 48 FMAs: keep VALU (and clocks) up
            x0 = __builtin_fmaf(x0, 1.000001f, 1e-7f);
            x1 = __builtin_fmaf(x1, 1.000001f, 1e-7f);
            x2 = __builtin_fmaf(x2, 1.000001f, 1e-7f);
            x3 = __builtin_fmaf(x3, 1.000001f, 1e-7f);
        }
    }
    asm volatile("" :: "v"(x0), "v"(x1), "v"(x2), "v"(x3));
    return false;   // hang guard: terminate (wrong) rather than hang
}

__global__ __launch_bounds__(256) void gru_xcd(
    const float* __restrict__ X_lag,                 // [120][256][32] f32
    const float* __restrict__ X_cov,                 // [120][256][32] f32
    const float* __restrict__ Wih0,                  // [1536][64] f32
    const unsigned short* __restrict__ Whh0,         // [1536][512] bf16
    const unsigned short* __restrict__ Wcat1,        // [1536][1024] bf16
    const float* __restrict__ bhh0,
    const float* __restrict__ bcomb0,                // b_ih0 + b_hh0(r,z)
    const float* __restrict__ bc1,
    const float* __restrict__ bhh1,
    unsigned short* __restrict__ out0,               // [256][120][512] bf16
    unsigned short* __restrict__ out1,               // [256][120][512] bf16
    int* __restrict__ flags,                         // [2][8][16] x FSTRIDE
    int* __restrict__ rolecnt)                       // [8] (x16 pad)
{
    __shared__ unsigned short wlds[96 * 520];        // ~97.5 KiB (hh weights)
    __shared__ float wih[96 * 68];                   // ~25.5 KiB (L0 ih weights)
    __shared__ int role_s;

    int xcd;
    asm("s_getreg_b32 %0, hwreg(20, 0, 32)" : "=s"(xcd));   // HW_REG_XCC_ID
    xcd &= 7;
    if (threadIdx.x == 0) role_s = atomicAdd(&rolecnt[xcd * 16], 1);
    __syncthreads();
    const int role = role_s;
    if (role >= 32) return;

    const int layer = role >> 4;
    const int jb    = role & 15;
    const int j0    = jb * 32;
    const int tid   = threadIdx.x;
    const int w     = tid >> 6, lane = tid & 63;
    const int l15   = lane & 15, l4 = lane >> 4;
    const int jt    = w & 1, bt = w >> 1;
    const int jloc  = jt * 16 + l15;                 // 0..31
    const int j     = j0 + jloc;
    const int bloc0 = bt * 16;                       // 0 or 16
    const int bg0   = xcd * 32;                      // global batch base

    // stage hh-part weights (96 rows x 512) into LDS, padded stride 520
    {
        const unsigned short* Wsrc = layer ? Wcat1 : Whh0;
        const int wstr = layer ? 1024 : 512;
        for (int c = tid; c < 96 * 64; c += 256) {
            int lr = c >> 6, ck = c & 63;
            int grow = (lr >> 5) * 512 + j0 + (lr & 31);
            bf16x8 v = *(const bf16x8*)(Wsrc + (size_t)grow * wstr + ck * 8);
            *(bf16x8*)&wlds[lr * 520 + ck * 8] = v;
        }
    }
    // L0 only: stage ih weights (96 rows x 64 f32), padded stride 68
    if (!layer) {
        for (int c = tid; c < 96 * 16; c += 256) {
            int row = c >> 4, q = c & 15;
            int grow = (row >> 5) * 512 + j0 + (row & 31);
            float4 v = *(const float4*)(Wih0 + (size_t)grow * 64 + q * 4);
            *(float4*)&wih[row * 68 + q * 4] = v;
        }
    }
    float bn_, br_ = 0.f, bz_ = 0.f, bnx_ = 0.f;
    if (layer) { br_ = bc1[j]; bz_ = bc1[512 + j]; bnx_ = bc1[1024 + j]; bn_ = bhh1[1024 + j]; }
    else       { br_ = bcomb0[j]; bz_ = bcomb0[512 + j]; bnx_ = bcomb0[1024 + j]; bn_ = bhh0[1024 + j]; }
    float carry[4] = {0.f, 0.f, 0.f, 0.f};

    const int* f0b = flags + (0 * 8 + xcd) * 16 * FSTRIDE;
    const int* f1b = flags + (1 * 8 + xcd) * 16 * FSTRIDE;
    int* myf = flags + ((layer * 8 + xcd) * 16 + jb) * FSTRIDE;
    __syncthreads();                                 // weights staged

    if (!layer) {
        // ============================ layer 0 ============================
        for (int t = 0; t < T_SEQ; t++) {
            // fused gx = x_t @ Wih0^T  (f32, no h dependency -> before wait)
            float dr[4] = {}, dz[4] = {}, dn[4] = {};
            #pragma unroll
            for (int kc = 0; kc < 16; kc++) {
                float4 w0 = *(const float4*)&wih[(0 * 32 + jloc) * 68 + kc * 4];
                float4 w1 = *(const float4*)&wih[(1 * 32 + jloc) * 68 + kc * 4];
                float4 w2 = *(const float4*)&wih[(2 * 32 + jloc) * 68 + kc * 4];
                #pragma unroll
                for (int rr = 0; rr < 4; rr++) {
                    int b = bg0 + bloc0 + 4 * l4 + rr;
                    const float* xr = (kc < 8)
                        ? X_lag + ((size_t)t * 256 + b) * 32 + kc * 4
                        : X_cov + ((size_t)t * 256 + b) * 32 + (kc - 8) * 4;
                    float4 xv = *(const float4*)xr;
                    dr[rr] += xv.x * w0.x + xv.y * w0.y + xv.z * w0.z + xv.w * w0.w;
                    dz[rr] += xv.x * w1.x + xv.y * w1.y + xv.z * w1.z + xv.w * w1.w;
                    dn[rr] += xv.x * w2.x + xv.y * w2.y + xv.z * w2.z + xv.w * w2.w;
                }
            }

            if (!wait16(f0b, t - 1, lane)) break;    // all h0(t-1) published

            f32x4 a0 = {0,0,0,0}, a1 = {0,0,0,0}, a2 = {0,0,0,0};
            if (t > 0) {
                bf16x8 Areg[16];
                #pragma unroll
                for (int ks = 0; ks < 16; ks++)
                    Areg[ks] = *(const bf16x8*)(out0 + ((size_t)(bg0 + bloc0 + l15) * T_SEQ + (t - 1)) * 512 + ks * 32 + 8 * l4);
                #pragma unroll
                for (int ks = 0; ks < 16; ks++) {
                    const int ko = ks * 32 + 8 * l4;
                    bf16x8 B0 = *(const bf16x8*)&wlds[(0 * 32 + jloc) * 520 + ko];
                    bf16x8 B1 = *(const bf16x8*)&wlds[(1 * 32 + jloc) * 520 + ko];
                    bf16x8 B2 = *(const bf16x8*)&wlds[(2 * 32 + jloc) * 520 + ko];
                    a0 = __builtin_amdgcn_mfma_f32_16x16x32_bf16(Areg[ks], B0, a0, 0, 0, 0);
                    a1 = __builtin_amdgcn_mfma_f32_16x16x32_bf16(Areg[ks], B1, a1, 0, 0, 0);
                    a2 = __builtin_amdgcn_mfma_f32_16x16x32_bf16(Areg[ks], B2, a2, 0, 0, 0);
                }
            }
            #pragma unroll
            for (int rr = 0; rr < 4; rr++) {
                int b = bg0 + bloc0 + 4 * l4 + rr;
                float r = sigm_fast(dr[rr] + br_ + a0[rr]);
                float z = sigm_fast(dz[rr] + bz_ + a1[rr]);
                float n = tanh_fast(dn[rr] + bnx_ + r * (a2[rr] + bn_));
                float h = (1.f - z) * n + z * carry[rr];
                carry[rr] = h;
                out0[((size_t)b * T_SEQ + t) * 512 + j] = f2bf(h);
            }
            asm volatile("s_waitcnt vmcnt(0)" ::: "memory");  // stores in L2
            __syncthreads();
            if (tid == 0)
                __hip_atomic_store(myf, t, __ATOMIC_RELAXED, __HIP_MEMORY_SCOPE_AGENT);
        }
    } else {
        // ============================ layer 1 ============================
        for (int t = 0; t < T_SEQ; t++) {
            f32x4 a0 = {0,0,0,0}, a1 = {0,0,0,0}, a2 = {0,0,0,0}, a3 = {0,0,0,0};
            // hh-part first: only needs own-layer flags >= t-1
            if (!wait16(f1b, t - 1, lane)) break;
            if (t > 0) {
                bf16x8 Areg[16];
                #pragma unroll
                for (int ks = 0; ks < 16; ks++)
                    Areg[ks] = *(const bf16x8*)(out1 + ((size_t)(bg0 + bloc0 + l15) * T_SEQ + (t - 1)) * 512 + ks * 32 + 8 * l4);
                #pragma unroll
                for (int ks = 0; ks < 16; ks++) {
                    const int ko = ks * 32 + 8 * l4;
                    bf16x8 B0 = *(const bf16x8*)&wlds[(0 * 32 + jloc) * 520 + ko];
                    bf16x8 B1 = *(const bf16x8*)&wlds[(1 * 32 + jloc) * 520 + ko];
                    bf16x8 B2 = *(const bf16x8*)&wlds[(2 * 32 + jloc) * 520 + ko];
                    a0 = __builtin_amdgcn_mfma_f32_16x16x32_bf16(Areg[ks], B0, a0, 0, 0, 0);
                    a1 = __builtin_amdgcn_mfma_f32_16x16x32_bf16(Areg[ks], B1, a1, 0, 0, 0);
                    a2 = __builtin_amdgcn_mfma_f32_16x16x32_bf16(Areg[ks], B2, a2, 0, 0, 0);
                }
            }
            // x-part: needs layer0 flags >= t
            if (!wait16(f0b, t, lane)) break;
            {
                bf16x8 Areg[16];
                #pragma unroll
                for (int ks = 0; ks < 16; ks++)
                    Areg[ks] = *(const bf16x8*)(out0 + ((size_t)(bg0 + bloc0 + l15) * T_SEQ + t) * 512 + ks * 32 + 8 * l4);
                #pragma unroll
                for (int ks = 0; ks < 16; ks++) {
                    const int ko = ks * 32 + 8 * l4;
                    const unsigned short* wb = Wcat1 + (size_t)j * 1024 + 512 + ko;
                    bf16x8 B0 = *(const bf16x8*)(wb);
                    bf16x8 B1 = *(const bf16x8*)(wb + 512 * 1024);
                    bf16x8 B2 = *(const bf16x8*)(wb + 1024 * 1024);
                    a0 = __builtin_amdgcn_mfma_f32_16x16x32_bf16(Areg[ks], B0, a0, 0, 0, 0);
                    a1 = __builtin_amdgcn_mfma_f32_16x16x32_bf16(Areg[ks], B1, a1, 0, 0, 0);
                    a3 = __builtin_amdgcn_mfma_f32_16x16x32_bf16(Areg[ks], B2, a3, 0, 0, 0);
                }
            }
            #pragma unroll
            for (int rr = 0; rr < 4; rr++) {
                int b = bg0 + bloc0 + 4 * l4 + rr;
                float r = sigm_fast(a0[rr] + br_);
                float z = sigm_fast(a1[rr] + bz_);
                float n = tanh_fast(a3[rr] + bnx_ + r * (a2[rr] + bn_));
                float h = (1.f - z) * n + z * carry[rr];
                carry[rr] = h;
                out1[((size_t)b * T_SEQ + t) * 512 + j] = f2bf(h);
            }
            asm volatile("s_waitcnt vmcnt(0)" ::: "memory");
            __syncthreads();
            if (tid == 0)
                __hip_atomic_store(myf, t, __ATOMIC_RELAXED, __HIP_MEMORY_SCOPE_AGENT);
        }
    }
}

// ---------------------------------------------------------------------------
// z partials (bf16 out reader): 960 blocks = (t, half, c-quarter).  [r8 ok]
// ---------------------------------------------------------------------------
__global__ __launch_bounds__(256) void zpart_kernel(
    const unsigned short* __restrict__ out, const float* __restrict__ Gw,
    float* __restrict__ zp)
{
    __shared__ float Os[128][33];
    __shared__ float Gs[128][33];
    int bk = blockIdx.x;
    int t = bk >> 3, half = (bk >> 2) & 1, cq = bk & 3;
    int tid = threadIdx.x;
    int tx = tid & 15, ty = tid >> 4;
    float acc[8][8] = {};
    int cbase = cq * 128;
    for (int c0 = cbase; c0 < cbase + 128; c0 += 32) {
        #pragma unroll
        for (int i = 0; i < 16; i++) {
            int e = tid + i * 256;
            int row = e >> 5, col = e & 31;
            Os[row][col] = bf2f(out[((size_t)(row + half * 128) * T_SEQ + t) * 512 + c0 + col]);
            float v = 0.f;
            if (row < 120)
                v = Gw[(size_t)row * KGATE + (size_t)t * 1024 + half * 512 + c0 + col];
            Gs[row][col] = v;
        }
        __syncthreads();
        #pragma unroll
        for (int kk = 0; kk < 32; kk++) {
            float a[8], g[8];
            #pragma unroll
            for (int i = 0; i < 8; i++) a[i] = Os[ty + i * 16][kk];
            #pragma unroll
            for (int j = 0; j < 8; j++) g[j] = Gs[tx + j * 16][kk];
            #pragma unroll
            for (int i = 0; i < 8; i++)
                #pragma unroll
                for (int j = 0; j < 8; j++) acc[i][j] += a[i] * g[j];
        }
        __syncthreads();
    }
    float* zb = zp + (size_t)bk * (128 * 120);
    #pragma unroll
    for (int i = 0; i < 8; i++) {
        int ii = ty + i * 16;
        #pragma unroll
        for (int j = 0; j < 8; j++) {
            int r = tx + j * 16;
            if (r < 120) zb[ii * 120 + r] = acc[i][j];
        }
    }
}

// 8 independent accumulators -> 8 outstanding loads/thread (BW-bound fix)
__global__ void zreduce(const float* __restrict__ zp,
                        const float* __restrict__ gate_b_l,
                        float* __restrict__ z)
{
    int idx = blockIdx.x * 256 + threadIdx.x;
    if (idx >= 128 * 120) return;
    const float* p = zp + idx;
    float s0 = 0, s1 = 0, s2 = 0, s3 = 0, s4 = 0, s5 = 0, s6 = 0, s7 = 0;
    for (int c = 0; c < 960; c += 8) {
        s0 += p[(size_t)(c + 0) * 15360];
        s1 += p[(size_t)(c + 1) * 15360];
        s2 += p[(size_t)(c + 2) * 15360];
        s3 += p[(size_t)(c + 3) * 15360];
        s4 += p[(size_t)(c + 4) * 15360];
        s5 += p[(size_t)(c + 5) * 15360];
        s6 += p[(size_t)(c + 6) * 15360];
        s7 += p[(size_t)(c + 7) * 15360];
    }
    z[idx] = ((s0 + s1) + (s2 + s3)) + ((s4 + s5) + (s6 + s7)) + gate_b_l[idx % 120];
}

__global__ __launch_bounds__(128) void bn_col(
    const float* __restrict__ z, const float* __restrict__ gamma,
    const float* __restrict__ beta, float* __restrict__ wm)
{
    int r = blockIdx.x, i = threadIdx.x;
    __shared__ float sh[2];
    float v = z[i * 120 + r];
    float s = v;
    for (int o = 32; o > 0; o >>= 1) s += __shfl_down(s, o);
    if ((i & 63) == 0) sh[i >> 6] = s;
    __syncthreads();
    float m = (sh[0] + sh[1]) * (1.f / 128.f);
    __syncthreads();
    float d = (v - m) * (v - m);
    for (int o = 32; o > 0; o >>= 1) d += __shfl_down(d, o);
    if ((i & 63) == 0) sh[i >> 6] = d;
    __syncthreads();
    float var = (sh[0] + sh[1]) * (1.f / 128.f);
    float w = 1.f / (1.f + expf(-(gamma[r] * (v - m) / sqrtf(var + 1e-5f) + beta[r])));
    __syncthreads();
    float ws_ = w;
    for (int o = 32; o > 0; o >>= 1) ws_ += __shfl_down(ws_, o);
    if ((i & 63) == 0) sh[i >> 6] = ws_;
    __syncthreads();
    if (i == 0) wm[r] = (sh[0] + sh[1]) * (1.f / 128.f);
}

__global__ __launch_bounds__(128) void softmax120(
    const float* __restrict__ wm, float* __restrict__ g_out,
    float* __restrict__ g_ws)
{
    int i = threadIdx.x;
    __shared__ float sh[2];
    float v = (i < 120) ? wm[i] : -1e30f;
    float m = v;
    for (int o = 32; o > 0; o >>= 1) m = fmaxf(m, __shfl_down(m, o));
    if ((i & 63) == 0) sh[i >> 6] = m;
    __syncthreads();
    float mx = fmaxf(sh[0], sh[1]);
    float e = (i < 120) ? expf(v - mx) : 0.f;
    __syncthreads();
    float se = e;
    for (int o = 32; o > 0; o >>= 1) se += __shfl_down(se, o);
    if ((i & 63) == 0) sh[i >> 6] = se;
    __syncthreads();
    float sum = sh[0] + sh[1];
    if (i < 120) { float g = e / sum; g_out[i] = g; g_ws[i] = g; }
}

__global__ void halfmeans(const unsigned short* __restrict__ out,
                          float* __restrict__ ms, float* __restrict__ mt)
{
    int idx = blockIdx.x * 256 + threadIdx.x;
    int half = idx >= TS;
    int tc = idx - half * TS;
    const unsigned short* base = out + (size_t)(half * 128) * TS + tc;
    float s = 0.f;
    for (int i = 0; i < 128; i++) s += bf2f(base[(size_t)i * TS]);
    s *= (1.f / 128.f);
    if (half) mt[tc] = s; else ms[tc] = s;
}

__global__ __launch_bounds__(512) void transfer_part(
    const float* __restrict__ ms, const float* __restrict__ mt,
    const float* __restrict__ gw, const int* __restrict__ lenw,
    float* __restrict__ part)
{
    int t = blockIdx.x, c = threadIdx.x;
    int lw = lenw[0];
    int j0 = t - lw; if (j0 < 0) j0 = 0;
    int j1 = t + lw; if (j1 > 119) j1 = 119;
    float m_c = ms[(size_t)t * 512 + c];
    float acc = 0.f;
    for (int j = j0; j <= j1; j++) {
        float d = m_c - mt[(size_t)j * 512 + c];
        acc += d * d;
    }
    for (int o = 32; o > 0; o >>= 1) acc += __shfl_down(acc, o);
    __shared__ float sh[8];
    if ((c & 63) == 0) sh[c >> 6] = acc;
    __syncthreads();
    if (c == 0) {
        float s = 0.f;
        #pragma unroll
        for (int k = 0; k < 8; k++) s += sh[k];
        part[t] = gw[t] * s;
    }
}

__global__ __launch_bounds__(256) void yhat_kernel(
    const unsigned short* __restrict__ out1, const float* __restrict__ y,
    const float* __restrict__ fcW, const float* __restrict__ fcb,
    int dsl, float* __restrict__ dout, float* __restrict__ lp_rows)
{
    int wid = blockIdx.x * 4 + (threadIdx.x >> 6);   // 0..dsl*256-1
    int lane = threadIdx.x & 63;
    int tt = wid >> 8, b = wid & 255;
    int t = T_SEQ - dsl + tt;
    const unsigned short* row = out1 + ((size_t)b * T_SEQ + t) * 512;
    float s = 0.f;
    #pragma unroll
    for (int k = 0; k < 8; k++) s += bf2f(row[lane + 64 * k]) * fcW[lane + 64 * k];
    for (int o = 32; o > 0; o >>= 1) s += __shfl_down(s, o);
    if (lane == 0) {
        float loc = s + fcb[0];
        float sp = fmaxf(loc, 0.f) + log1pf(expf(-fabsf(loc)));
        float scale = sp + 1e-6f;
        dout[2 + tt * 256 + b] = loc;
        dout[2 + dsl * 256 + tt * 256 + b] = scale;
        float yt = y[(size_t)t * 256 + b];
        float u = (yt - loc) / scale;
        lp_rows[wid] = -0.5f * u * u - logf(scale) - 0.91893853320467274f;
    }
}

__global__ __launch_bounds__(64) void finalize(
    const float* __restrict__ lp_rows, const float* __restrict__ part0,
    const float* __restrict__ part1, float* __restrict__ dout, int n_lp)
{
    int i = threadIdx.x;
    float s = 0.f;
    for (int k = i; k < n_lp; k += 64) s += lp_rows[k];
    for (int o = 32; o > 0; o >>= 1) s += __shfl_down(s, o);
    float tr = 0.f;
    for (int k = i; k < 120; k += 64) tr += part0[k] + part1[k];
    for (int o = 32; o > 0; o >>= 1) tr += __shfl_down(tr, o);
    if (i == 0) {
        float ly = -s / (float)n_lp;
        dout[1] = ly;
        dout[0] = ly + tr;
    }
}

// ---------------------------------------------------------------------------
extern "C" void kernel_launch(void* const* d_in, const int* in_sizes, int n_in,
                              void* d_out, int out_size, void* d_ws, size_t ws_size,
                              hipStream_t stream)
{
    const float* X_cov  = (const float*)d_in[1];
    const float* X_lag  = (const float*)d_in[2];
    const float* y      = (const float*)d_in[3];
    const int*   lenw   = (const int*)d_in[5];
    const float* W_ih0  = (const float*)d_in[6];
    const float* W_hh0  = (const float*)d_in[7];
    const float* b_ih0  = (const float*)d_in[8];
    const float* b_hh0  = (const float*)d_in[9];
    const float* W_ih1  = (const float*)d_in[10];
    const float* W_hh1  = (const float*)d_in[11];
    const float* b_ih1  = (const float*)d_in[12];
    const float* b_hh1  = (const float*)d_in[13];
    const float* gate_W = (const float*)d_in[14];
    const float* gate_b = (const float*)d_in[15];
    const float* bn_g   = (const float*)d_in[16];
    const float* bn_b   = (const float*)d_in[17];
    const float* fc_W   = (const float*)d_in[18];
    const float* fc_b   = (const float*)d_in[19];
    float* dout = (float*)d_out;
    float* ws   = (float*)d_ws;

    // workspace layout (float offsets) -- no gx0 buffer anymore
    unsigned short* out0  = (unsigned short*)(ws);                // 15,728,640 ush
    unsigned short* out1  = (unsigned short*)(ws + 7864320);      // 15,728,640 ush
    unsigned short* Whh0bf  = (unsigned short*)(ws + 15728640);   // 786,432 ush
    unsigned short* Wcat1bf = (unsigned short*)(ws + 16121856);   // 1,572,864 ush
    float* zp      = ws + 16908288;               // 14,745,600
    float* zmat    = ws + 31653888;               // 15,360
    float* wm      = ws + 31669248;               // 120
    float* gw_ws   = ws + 31669368;               // 240
    float* msb     = ws + 31669608;               // 61,440
    float* mtb     = ws + 31731048;               // 61,440
    float* part    = ws + 31792488;               // 240
    float* bcomb0  = ws + 31792728;               // 1536
    float* bc1     = ws + 31794264;               // 1536
    int*   flags   = (int*)(ws + 31795800);       // 4096 ints
    int*   rolecnt = (int*)(ws + 31799896);       // 128 ints
    float* lp_rows = ws + 31800024;               // 6144

    int dsl = (out_size - 2 - 2 * T_SEQ) / (2 * BATCH);   // = 24

    cast_whh0<<<dim3(3072), 256, 0, stream>>>(W_hh0, Whh0bf);
    cast_wcat1<<<dim3(6144), 256, 0, stream>>>(W_hh1, W_ih1, Wcat1bf);
    mkbias<<<dim3(6), 256, 0, stream>>>(b_ih0, b_hh0, b_ih1, b_hh1, bcomb0, bc1);
    hipMemsetAsync(flags, 0xFF, 4096 * sizeof(int), stream);   // flags = -1
    hipMemsetAsync(rolecnt, 0, 128 * sizeof(int), stream);

    gru_xcd<<<dim3(320), 256, 0, stream>>>(X_lag, X_cov, W_ih0,
                                           Whh0bf, Wcat1bf,
                                           b_hh0, bcomb0, bc1, b_hh1,
                                           out0, out1, flags, rolecnt);

    for (int l = 0; l < 2; l++) {
        const unsigned short* o = l ? out1 : out0;
        zpart_kernel<<<960, 256, 0, stream>>>(o, gate_W + (size_t)l * 120 * KGATE, zp);
        zreduce<<<60, 256, 0, stream>>>(zp, gate_b + l * 120, zmat);
        bn_col<<<120, 128, 0, stream>>>(zmat, bn_g + l * 120, bn_b + l * 120, wm);
        softmax120<<<1, 128, 0, stream>>>(wm, dout + 2 + 2 * dsl * 256 + l * 120,
                                          gw_ws + l * 120);
        halfmeans<<<480, 256, 0, stream>>>(o, msb, mtb);
        transfer_part<<<120, 512, 0, stream>>>(msb, mtb, gw_ws + l * 120, lenw,
                                               part + l * 120);
    }

    yhat_kernel<<<dsl * 64, 256, 0, stream>>>(out1, y, fc_W, fc_b, dsl, dout, lp_rows);
    finalize<<<1, 64, 0, stream>>>(lp_rows, part, part + 120, dout, dsl * 256);
}